// Round 5
// baseline (1812.794 us; speedup 1.0000x reference)
//
#include <hip/hip_runtime.h>

#define A_DIM 64
#define B_DIM 128
#define E 128
#define NG 50
#define NROW (A_DIM*A_DIM*B_DIM)   // 524288
#define TR 64                      // rows per block
#define KS 136                     // tc/xb row stride (shorts): 16B-aligned rows
#define SMS 72                     // sm row stride (shorts)
#define WBLK 512                   // shorts per (grp,plane,ksub) W fragment block (1 KB)
#define BR_STRIDE 147456           // shorts per branch: 18 chunks x 16 blocks x 512
#define NOUT (B_DIM + A_DIM*B_DIM*3)   // 24704 output floats
#define WLSCALE 64.0f              // W-lo pre-scale (avoids fp16 subnormal flush)
#define WLINV   0.015625f          // 1/64

using half8   = _Float16 __attribute__((ext_vector_type(8)));
using short8v = short __attribute__((ext_vector_type(8)));
using f32x16  = float __attribute__((ext_vector_type(16)));

__device__ __forceinline__ float silu_f(float x) {
  return x * __builtin_amdgcn_rcpf(1.0f + __expf(-x));
}
__device__ __forceinline__ short hbits(_Float16 h) {
  return (short)__builtin_bit_cast(unsigned short, h);
}

// 4 B-fragments of one K=32 chunk (hi ksub0/1, lo ksub0/1) = 16 VGPRs
struct WFrag { half8 h0, h1, l0, l1; };

__device__ __forceinline__ WFrag load_wfrag(const short* __restrict__ wlb, int cidx) {
  const short* p = wlb + (size_t)cidx * (16 * WBLK);
  WFrag w;
  w.h0 = __builtin_bit_cast(half8, *(const short8v*)(p + 0 * WBLK));
  w.h1 = __builtin_bit_cast(half8, *(const short8v*)(p + 1 * WBLK));
  w.l0 = __builtin_bit_cast(half8, *(const short8v*)(p + 2 * WBLK));
  w.l1 = __builtin_bit_cast(half8, *(const short8v*)(p + 3 * WBLK));
  return w;
}

// One K=32 chunk, 2-term fp16: acc += a*Wh ; accl += a*(Wl*64). A from LDS.
__device__ __forceinline__ void gemm_w(
    const short* __restrict__ xsrc, int xstr, int kcol,
    const WFrag& w, f32x16 acc[2], f32x16 accl[2], int l31, int l5)
{
  #pragma unroll
  for (int rt = 0; rt < 2; ++rt) {
    const short* arow = xsrc + (rt * 32 + l31) * xstr + kcol + l5 * 8;
    half8 a0 = __builtin_bit_cast(half8, *(const short8v*)arow);
    half8 a1 = __builtin_bit_cast(half8, *(const short8v*)(arow + 16));
    acc[rt]  = __builtin_amdgcn_mfma_f32_32x32x16_f16(a0, w.h0, acc[rt],  0, 0, 0);
    accl[rt] = __builtin_amdgcn_mfma_f32_32x32x16_f16(a0, w.l0, accl[rt], 0, 0, 0);
    acc[rt]  = __builtin_amdgcn_mfma_f32_32x32x16_f16(a1, w.h1, acc[rt],  0, 0, 0);
    accl[rt] = __builtin_amdgcn_mfma_f32_32x32x16_f16(a1, w.l1, accl[rt], 0, 0, 0);
  }
}

// Transpose + fp16 hi / scaled-lo split of all weights into lane-ordered
// fragment blocks. blk = cidx*16 + grp*4 + p*2 + ksub; lane = (n&31)+32*((kk>>3)&1).
// Blocks >= 576 zero the output buffer instead (fused zero_out).
__global__ __launch_bounds__(256) void prep_weights(
    const float* __restrict__ eWin, const float* __restrict__ eWh,
    const float* __restrict__ eWout, const float* __restrict__ erbf,
    const float* __restrict__ fWin, const float* __restrict__ fWh,
    const float* __restrict__ fWout, const float* __restrict__ frbf,
    short* __restrict__ S, float* __restrict__ out)
{
  if (blockIdx.x >= 576) {
    int i = (blockIdx.x - 576) * 256 + threadIdx.x;
    if (i < NOUT) out[i] = 0.0f;
    return;
  }
  int o = blockIdx.x * 256 + threadIdx.x;
  int br = (o >= 73728) ? 1 : 0;
  int r = o - br * 73728;
  short* base = S + br * BR_STRIDE;
  float v; int cidx, n, kk;
  if (r < 65536) {
    int lay = r >> 14, idx = r & 16383;
    int k = idx >> 7; n = idx & 127;
    const float* W = (lay == 0) ? (br ? fWin : eWin)
                   : (lay == 3) ? (br ? fWout : eWout)
                   : ((br ? fWh : eWh) + (lay - 1) * 16384);
    v = W[k * 128 + n];
    cidx = lay * 4 + (k >> 5); kk = k & 31;
  } else {
    int rr = r - 65536;                 // 0..8191
    int k = rr >> 7; n = rr & 127;
    v = (k < NG) ? (br ? frbf : erbf)[k * 128 + n] : 0.0f;
    cidx = 16 + (k >> 5); kk = k & 31;
  }
  int blk = cidx * 16 + (n >> 5) * 4 + (kk >> 4);                    // p = 0
  int idx2 = blk * WBLK + ((n & 31) + 32 * ((kk >> 3) & 1)) * 8 + (kk & 7);
  _Float16 wh = (_Float16)v;
  _Float16 wl = (_Float16)((v - (float)wh) * WLSCALE);
  base[idx2] = hbits(wh);
  base[idx2 + 2 * WBLK] = hbits(wl);                                 // p = 1
}

__global__ __launch_bounds__(256, 3) void fused_main(
    const float* __restrict__ T, const float* __restrict__ mask,
    const float* __restrict__ dist, const float* __restrict__ vh,
    const float* __restrict__ ebin, const float* __restrict__ ebh,
    const float* __restrict__ ebout, const float* __restrict__ ehead,
    const float* __restrict__ fbin, const float* __restrict__ fbh,
    const float* __restrict__ fbout, const float* __restrict__ fhead,
    const short* __restrict__ S,
    float* __restrict__ out)
{
  __shared__ short tc[TR * KS];       // pristine T fp16: 17408 B
  __shared__ short xb[TR * KS];       // activations:     17408 B
  __shared__ short sm[TR * SMS];      // smeared:          9216 B
  __shared__ float part[4][TR];       //                   1024 B -> 45056 B (3 blk/CU)

  const int t = threadIdx.x;
  const int wave = t >> 6, lane = t & 63;
  const int l31 = lane & 31, l5 = lane >> 5;
  const long r0g = (long)blockIdx.x * TR;

  // ---- T tile -> tc fp16 plane (once, shared by both branches) ----
  {
    int row = t >> 2, seg = t & 3;
    const float* Tp = T + (r0g + row) * E + seg * 32;
    short* ph = tc + row * KS + seg * 32;
    #pragma unroll
    for (int j = 0; j < 8; ++j) {
      float4 v = *(const float4*)(Tp + j * 4);
      short4 s4 = make_short4(hbits((_Float16)v.x), hbits((_Float16)v.y),
                              hbits((_Float16)v.z), hbits((_Float16)v.w));
      *(short4*)(ph + j * 4) = s4;
    }
  }
  // ---- smeared gaussians -> sm (once, shared by both branches) ----
  {
    const float stepv = 12.0f / 49.0f;
    const float coeff = -0.5f / (stepv * stepv);
    int r = t & 63, kg = t >> 6;
    float d = dist[r0g + r];
    #pragma unroll
    for (int j4 = 0; j4 < 4; ++j4) {
      float vv[4];
      #pragma unroll
      for (int jj = 0; jj < 4; ++jj) {
        int k = kg * 16 + j4 * 4 + jj;
        float dd = d - (float)k * stepv;
        vv[jj] = (k < NG) ? __expf(coeff * dd * dd) : 0.0f;
      }
      short4 s4 = make_short4(hbits((_Float16)vv[0]), hbits((_Float16)vv[1]),
                              hbits((_Float16)vv[2]), hbits((_Float16)vv[3]));
      *(short4*)(sm + r * SMS + kg * 16 + j4 * 4) = s4;
    }
  }

  #pragma unroll 1
  for (int br2 = 0; br2 < 2; ++br2) {
    const short* wlb = S + br2 * BR_STRIDE + wave * (4 * WBLK) + lane * 8;
    const float* bin  = br2 ? fbin : ebin;
    const float* bh_  = br2 ? fbh : ebh;
    const float* bout = br2 ? fbout : ebout;
    const float* head = br2 ? fhead : ehead;

    WFrag wc = load_wfrag(wlb, 0);    // chunk-0 prefetch
    f32x16 acc[2], accl[2];
    float xres[2][16];

    #pragma unroll 1
    for (int lay = 0; lay < 4; ++lay) {
      const float* bg = (lay == 0) ? bin : (lay == 3) ? bout : (bh_ + (lay - 1) * E);
      float b0 = bg[wave * 32 + l31];
      #pragma unroll
      for (int i = 0; i < 16; ++i) {
        acc[0][i] = b0; acc[1][i] = b0;
        accl[0][i] = 0.f; accl[1][i] = 0.f;
      }
      __syncthreads();                 // (a) staging / prev epilogue visible
      const short* xsrc = (lay == 0) ? tc : xb;
      #pragma unroll
      for (int ch = 0; ch < 4; ++ch) {
        WFrag wn = load_wfrag(wlb, lay * 4 + ch + 1);  // 1..16 — next-chunk prefetch
        gemm_w(xsrc, KS, ch * 32, wc, acc, accl, l31, l5);
        wc = wn;
      }
      if (lay < 3) {
        __syncthreads();               // (b) all xb/tc reads of this layer done
        #pragma unroll
        for (int rt = 0; rt < 2; ++rt)
          #pragma unroll
          for (int rg = 0; rg < 16; ++rg) {
            float y = acc[rt][rg] + accl[rt][rg] * WLINV;
            float v = silu_f(y);
            if (lay > 0) v += xres[rt][rg];
            xres[rt][rg] = v;
            int rowa = rt * 32 + 4 * l5 + (rg & 3) + 8 * (rg >> 2);
            xb[rowa * KS + wave * 32 + l31] = hbits((_Float16)v);
          }
      }
    }
    // wc == rbf chunk 16; fold feat
    #pragma unroll
    for (int rt = 0; rt < 2; ++rt)
      #pragma unroll
      for (int i = 0; i < 16; ++i) acc[rt][i] += accl[rt][i] * WLINV;

    WFrag w17 = load_wfrag(wlb, 17);
    f32x16 acc2[2], acc2l[2];
    #pragma unroll
    for (int i = 0; i < 16; ++i) {
      acc2[0][i] = 0.f; acc2[1][i] = 0.f;
      acc2l[0][i] = 0.f; acc2l[1][i] = 0.f;
    }
    gemm_w(sm, SMS, 0,  wc,  acc2, acc2l, l31, l5);
    gemm_w(sm, SMS, 32, w17, acc2, acc2l, l31, l5);

    float h0 = head[wave * 32 + l31];
    #pragma unroll
    for (int rt = 0; rt < 2; ++rt)
      #pragma unroll
      for (int rg = 0; rg < 16; ++rg) {
        float rb = acc2[rt][rg] + acc2l[rt][rg] * WLINV;
        float p = acc[rt][rg] * rb * h0;
        p += __shfl_xor(p, 1); p += __shfl_xor(p, 2);
        p += __shfl_xor(p, 4); p += __shfl_xor(p, 8);
        p += __shfl_xor(p, 16);
        if (l31 == 0)
          part[wave][rt * 32 + 4 * l5 + (rg & 3) + 8 * (rg >> 2)] = p;
      }
    __syncthreads();                   // (c) part visible
    if (t < TR) {
      long g = r0g + t;
      float pr = part[0][t] + part[1][t] + part[2][t] + part[3][t];
      float pm = pr * mask[g];
      if (br2 == 0) {
        atomicAdd(out + (int)(g & 127), pm * (1.0f / 3600.0f));
      } else {
        int b = (int)(g & 127);
        int j = (int)((g >> 7) & 63);
        float s = pm * (1.0f / 60.0f);
        float* fo = out + B_DIM + (j * B_DIM + b) * 3;
        atomicAdd(fo + 0, s * vh[g * 3 + 0]);
        atomicAdd(fo + 1, s * vh[g * 3 + 1]);
        atomicAdd(fo + 2, s * vh[g * 3 + 2]);
      }
    }
    // next-branch part[] writes are ordered after (a) of its lay0 -> no race
  }
}

extern "C" void kernel_launch(void* const* d_in, const int* in_sizes, int n_in,
                              void* d_out, int out_size, void* d_ws, size_t ws_size,
                              hipStream_t stream) {
  const float* T    = (const float*)d_in[0];
  const float* mask = (const float*)d_in[1];
  const float* dist = (const float*)d_in[2];
  const float* vh   = (const float*)d_in[3];
  const float* eWin = (const float*)d_in[4];
  const float* ebin = (const float*)d_in[5];
  const float* eWh  = (const float*)d_in[6];
  const float* ebh  = (const float*)d_in[7];
  const float* eWout= (const float*)d_in[8];
  const float* ebout= (const float*)d_in[9];
  const float* erbf = (const float*)d_in[10];
  const float* ehead= (const float*)d_in[11];
  const float* fWin = (const float*)d_in[12];
  const float* fbin = (const float*)d_in[13];
  const float* fWh  = (const float*)d_in[14];
  const float* fbh  = (const float*)d_in[15];
  const float* fWout= (const float*)d_in[16];
  const float* fbout= (const float*)d_in[17];
  const float* frbf = (const float*)d_in[18];
  const float* fhead= (const float*)d_in[19];

  short* S = (short*)d_ws;                 // 576 KB of workspace
  float* out = (float*)d_out;

  prep_weights<<<576 + (NOUT + 255) / 256, 256, 0, stream>>>(
      eWin, eWh, eWout, erbf, fWin, fWh, fWout, frbf, S, out);
  fused_main<<<NROW / TR, 256, 0, stream>>>(
      T, mask, dist, vh,
      ebin, ebh, ebout, ehead,
      fbin, fbh, fbout, fhead,
      S, out);
}